// Round 4
// baseline (495.078 us; speedup 1.0000x reference)
//
#include <hip/hip_runtime.h>
#include <math.h>

#define NQ    6
#define QDIM  64
#define BB    128
#define CC    64
#define TT    2048
#define DD    256
#define NCH   128
#define CHLEN 16
#define HH    128
#define NCP   60
#define GRID1 768     // persistent K1 grid: 3 blocks/CU x 256 CU
#define NTASK 8192    // 128 b x 64 chunk-pairs

typedef __bf16 bf16x8 __attribute__((ext_vector_type(8)));
typedef float  f32x4  __attribute__((ext_vector_type(4)));

__device__ __forceinline__ float fast_tanh(float x) {
  float e = __expf(2.f * x);
  return 1.f - 2.f / (e + 1.f);
}

__device__ __forceinline__ float wave_sum(float v) {
#pragma unroll
  for (int off = 32; off >= 1; off >>= 1) v += __shfl_xor(v, off, 64);
  return v;
}

// ---- quantum gates: one statevector per wave, (re,im) per lane ----
__device__ __forceinline__ void g_rx(float& re, float& im, int lane, int m, float half) {
  float c = __cosf(half), s = __sinf(half);
  float pre = __shfl_xor(re, m, 64);
  float pim = __shfl_xor(im, m, 64);
  float nre = c * re + s * pim;
  float nim = c * im - s * pre;
  re = nre; im = nim;
}
__device__ __forceinline__ void g_ry(float& re, float& im, int lane, int m, float half) {
  float c = __cosf(half), s = __sinf(half);
  float pre = __shfl_xor(re, m, 64);
  float pim = __shfl_xor(im, m, 64);
  float sg = (lane & m) ? s : -s;
  re = c * re + sg * pre;
  im = c * im + sg * pim;
}
__device__ __forceinline__ void g_rz(float& re, float& im, int lane, int m, float half) {
  float c = __cosf(half), s = __sinf(half);
  float sg = (lane & m) ? s : -s;
  float nre = c * re - sg * im;
  float nim = c * im + sg * re;
  re = nre; im = nim;
}
__device__ __forceinline__ void g_crx(float& re, float& im, int lane, int mc, int mt, float half) {
  float c = __cosf(half), s = __sinf(half);
  float pre = __shfl_xor(re, mt, 64);
  float pim = __shfl_xor(im, mt, 64);
  if (lane & mc) {
    float nre = c * re + s * pim;
    float nim = c * im - s * pre;
    re = nre; im = nim;
  }
}
__device__ __forceinline__ void ansatz_layer(float& re, float& im, int lane,
                                             const float* p) {
#pragma unroll
  for (int q = 0; q < 6; ++q) {
    int m = 1 << (5 - q);
    g_rx(re, im, lane, m, 0.5f * p[3 * q + 0]);
    g_ry(re, im, lane, m, 0.5f * p[3 * q + 1]);
    g_rz(re, im, lane, m, 0.5f * p[3 * q + 2]);
  }
#pragma unroll
  for (int q = 0; q < 6; ++q)
    g_crx(re, im, lane, 1 << (5 - q), 1 << (5 - ((q + 1) % 6)), 0.5f * p[18 + q]);
#pragma unroll
  for (int q = 5; q >= 0; --q)
    g_crx(re, im, lane, 1 << (5 - q), 1 << (5 - ((q + 5) % 6)), 0.5f * p[24 + (5 - q)]);
}

// ============ K0: one-time weight prep: split-bf16 + transpose ============
__global__ __launch_bounds__(256) void k0_prep(
    const float* __restrict__ emb_w, const float* __restrict__ att_w1,
    const float* __restrict__ proj_w,
    __bf16* __restrict__ embH, __bf16* __restrict__ embL,
    __bf16* __restrict__ attH, __bf16* __restrict__ attL,
    __bf16* __restrict__ projTH, __bf16* __restrict__ projTL) {
  int idx = blockIdx.x * 256 + threadIdx.x;
  if (idx < 16384) {                       // emb: 256d x 64k
    int d = idx >> 6, k = idx & 63;
    float v = emb_w[k * 256 + d];
    __bf16 h = (__bf16)v;
    embH[idx] = h; embL[idx] = (__bf16)(v - (float)h);
  } else if (idx < 49152) {                // att: 128j x 256d
    int i = idx - 16384;
    int j = i >> 8, d = i & 255;
    float v = att_w1[d * 128 + j];
    __bf16 h = (__bf16)v;
    attH[i] = h; attL[i] = (__bf16)(v - (float)h);
  } else {                                 // projT: 64n x 256d (rows>=60 zero)
    int i = idx - 49152;
    int n = i >> 8, d = i & 255;
    float v = (n < 60) ? proj_w[d * 60 + n] : 0.f;
    __bf16 h = (__bf16)v;
    projTH[i] = h; projTL[i] = (__bf16)(v - (float)h);
  }
}

// ============ K1: persistent, grid-stride over 8192 chunk-pair tasks ============
// Split-bf16 3-product MFMA. m89 layouts: A[m=lane&15][k=quad*8+j],
// B[n=lane&15][k=quad*8+j], C: n=lane&15, m=quad*4+reg.
// GEMM1 B-frags + epilogue constants are loop-invariant registers;
// x prefetched one task ahead; GEMM2/proj B-streams double-buffered.
__global__ __launch_bounds__(256, 3) void k1_feats_attn_proj(
    const float* __restrict__ x, const float* __restrict__ emb_b,
    const float* __restrict__ att_b1, const float* __restrict__ att_w2,
    const float* __restrict__ proj_b,
    const __bf16* __restrict__ embH, const __bf16* __restrict__ embL,
    const __bf16* __restrict__ attH, const __bf16* __restrict__ attL,
    const __bf16* __restrict__ projTH, const __bf16* __restrict__ projTL,
    float* __restrict__ params_out) {
  const int tid = threadIdx.x, wv = tid >> 6, lane = tid & 63;
  const int l15 = lane & 15, quad = lane >> 4;

  __shared__ float  xtile[32][68];
  __shared__ __bf16 fH[32][264];
  __shared__ __bf16 fL[32][264];
  __shared__ float  scoreP[4][32];
  __shared__ float  wSm[2][16];
  __shared__ float  chunkS[2][256];

  // ---- loop-invariant weight fragments & constants ----
  bf16x8 e_bh[4][2], e_bl[4][2];
#pragma unroll
  for (int nt = 0; nt < 4; ++nt) {
    const size_t row = (size_t)(wv * 64 + nt * 16 + l15) * 64 + 8 * quad;
#pragma unroll
    for (int s = 0; s < 2; ++s) {
      e_bh[nt][s] = *(const bf16x8*)(embH + row + 32 * s);
      e_bl[nt][s] = *(const bf16x8*)(embL + row + 32 * s);
    }
  }
  float biasv[4];
#pragma unroll
  for (int nt = 0; nt < 4; ++nt) biasv[nt] = emb_b[wv * 64 + nt * 16 + l15];
  float w2v[2], b1v[2];
#pragma unroll
  for (int jt = 0; jt < 2; ++jt) {
    int j = wv * 32 + jt * 16 + l15;
    w2v[jt] = att_w2[j];
    b1v[jt] = att_b1[j];
  }
  const int jout = wv * 16 + l15;
  const float pbias = (jout < 60) ? proj_b[jout] : 0.f;

  // ---- x prefetch for first task ----
  const int xk = tid >> 3, xt4 = tid & 7;
  float4 xv0, xv1;
  {
    int b = blockIdx.x >> 6, cp = blockIdx.x & 63;
    const float* base = x + (size_t)(b * 64) * 2048 + cp * 32 + xt4 * 4;
    xv0 = *(const float4*)(base + (size_t)xk * 2048);
    xv1 = *(const float4*)(base + (size_t)(xk + 32) * 2048);
  }

  for (int tk = blockIdx.x; tk < NTASK; tk += GRID1) {
    // stage prefetched x into xtile
    xtile[xt4 * 4 + 0][xk] = xv0.x; xtile[xt4 * 4 + 1][xk] = xv0.y;
    xtile[xt4 * 4 + 2][xk] = xv0.z; xtile[xt4 * 4 + 3][xk] = xv0.w;
    xtile[xt4 * 4 + 0][xk + 32] = xv1.x; xtile[xt4 * 4 + 1][xk + 32] = xv1.y;
    xtile[xt4 * 4 + 2][xk + 32] = xv1.z; xtile[xt4 * 4 + 3][xk + 32] = xv1.w;
    __syncthreads();

    // issue next task's x loads (latency hidden behind this iteration)
    {
      int tk2 = tk + GRID1;
      if (tk2 < NTASK) {
        int b = tk2 >> 6, cp = tk2 & 63;
        const float* base = x + (size_t)(b * 64) * 2048 + cp * 32 + xt4 * 4;
        xv0 = *(const float4*)(base + (size_t)xk * 2048);
        xv1 = *(const float4*)(base + (size_t)(xk + 32) * 2048);
      }
    }

    // ---- GEMM1: feats[32][256], per-mt to bound registers ----
#pragma unroll
    for (int mt = 0; mt < 2; ++mt) {
      bf16x8 ah[2], al[2];
#pragma unroll
      for (int s = 0; s < 2; ++s) {
        const float* src = &xtile[mt * 16 + l15][32 * s + 8 * quad];
        float4 u0 = *(const float4*)src, u1 = *(const float4*)(src + 4);
        float vals[8] = {u0.x, u0.y, u0.z, u0.w, u1.x, u1.y, u1.z, u1.w};
#pragma unroll
        for (int j = 0; j < 8; ++j) {
          __bf16 h = (__bf16)vals[j];
          ah[s][j] = h;
          al[s][j] = (__bf16)(vals[j] - (float)h);
        }
      }
      f32x4 acc[4];
#pragma unroll
      for (int nt = 0; nt < 4; ++nt) acc[nt] = (f32x4){0.f, 0.f, 0.f, 0.f};
#pragma unroll
      for (int nt = 0; nt < 4; ++nt) {
        acc[nt] = __builtin_amdgcn_mfma_f32_16x16x32_bf16(ah[0], e_bh[nt][0], acc[nt], 0, 0, 0);
        acc[nt] = __builtin_amdgcn_mfma_f32_16x16x32_bf16(al[0], e_bh[nt][0], acc[nt], 0, 0, 0);
        acc[nt] = __builtin_amdgcn_mfma_f32_16x16x32_bf16(ah[0], e_bl[nt][0], acc[nt], 0, 0, 0);
        acc[nt] = __builtin_amdgcn_mfma_f32_16x16x32_bf16(ah[1], e_bh[nt][1], acc[nt], 0, 0, 0);
        acc[nt] = __builtin_amdgcn_mfma_f32_16x16x32_bf16(al[1], e_bh[nt][1], acc[nt], 0, 0, 0);
        acc[nt] = __builtin_amdgcn_mfma_f32_16x16x32_bf16(ah[1], e_bl[nt][1], acc[nt], 0, 0, 0);
      }
#pragma unroll
      for (int nt = 0; nt < 4; ++nt) {
        int d = wv * 64 + nt * 16 + l15;
#pragma unroll
        for (int r = 0; r < 4; ++r) {
          int trow = mt * 16 + quad * 4 + r;
          float v = acc[nt][r] + biasv[nt];
          __bf16 h = (__bf16)v;
          fH[trow][d] = h;
          fL[trow][d] = (__bf16)(v - (float)h);
        }
      }
    }
    __syncthreads();

    // ---- GEMM2: h = tanh(feats @ att_w1 + b1), fused scores; B double-buffered ----
    {
      f32x4 acc2[2][2];
#pragma unroll
      for (int mt = 0; mt < 2; ++mt)
#pragma unroll
        for (int jt = 0; jt < 2; ++jt) acc2[mt][jt] = (f32x4){0.f, 0.f, 0.f, 0.f};
      bf16x8 g_bh[2][2], g_bl[2][2];  // [buf][jt]
#pragma unroll
      for (int jt = 0; jt < 2; ++jt) {
        const size_t row = (size_t)(wv * 32 + jt * 16 + l15) * 256 + 8 * quad;
        g_bh[0][jt] = *(const bf16x8*)(attH + row);
        g_bl[0][jt] = *(const bf16x8*)(attL + row);
      }
#pragma unroll
      for (int s = 0; s < 8; ++s) {
        const int cb = s & 1, nb = cb ^ 1;
        if (s < 7) {
#pragma unroll
          for (int jt = 0; jt < 2; ++jt) {
            const size_t row = (size_t)(wv * 32 + jt * 16 + l15) * 256 + 32 * (s + 1) + 8 * quad;
            g_bh[nb][jt] = *(const bf16x8*)(attH + row);
            g_bl[nb][jt] = *(const bf16x8*)(attL + row);
          }
        }
        bf16x8 fa[2], fb[2];
#pragma unroll
        for (int mt = 0; mt < 2; ++mt) {
          fa[mt] = *(const bf16x8*)&fH[mt * 16 + l15][32 * s + 8 * quad];
          fb[mt] = *(const bf16x8*)&fL[mt * 16 + l15][32 * s + 8 * quad];
        }
#pragma unroll
        for (int jt = 0; jt < 2; ++jt)
#pragma unroll
          for (int mt = 0; mt < 2; ++mt) {
            acc2[mt][jt] = __builtin_amdgcn_mfma_f32_16x16x32_bf16(fa[mt], g_bh[cb][jt], acc2[mt][jt], 0, 0, 0);
            acc2[mt][jt] = __builtin_amdgcn_mfma_f32_16x16x32_bf16(fb[mt], g_bh[cb][jt], acc2[mt][jt], 0, 0, 0);
            acc2[mt][jt] = __builtin_amdgcn_mfma_f32_16x16x32_bf16(fa[mt], g_bl[cb][jt], acc2[mt][jt], 0, 0, 0);
          }
      }
#pragma unroll
      for (int mt = 0; mt < 2; ++mt)
#pragma unroll
        for (int r = 0; r < 4; ++r) {
          float sc = fast_tanh(acc2[mt][0][r] + b1v[0]) * w2v[0] +
                     fast_tanh(acc2[mt][1][r] + b1v[1]) * w2v[1];
          sc += __shfl_xor(sc, 1, 64);
          sc += __shfl_xor(sc, 2, 64);
          sc += __shfl_xor(sc, 4, 64);
          sc += __shfl_xor(sc, 8, 64);
          if (l15 == 0) scoreP[wv][mt * 16 + quad * 4 + r] = sc;
        }
    }
    __syncthreads();

    if (tid < 2) {  // softmax over 16 per chunk (att_b2 dropped: shift-invariant)
      float s[16], mx = -1e30f;
#pragma unroll
      for (int t = 0; t < 16; ++t) {
        int tt = tid * 16 + t;
        s[t] = (scoreP[0][tt] + scoreP[1][tt]) + (scoreP[2][tt] + scoreP[3][tt]);
        mx = fmaxf(mx, s[t]);
      }
      float sum = 0.f;
#pragma unroll
      for (int t = 0; t < 16; ++t) { s[t] = __expf(s[t] - mx); sum += s[t]; }
      float inv = 1.f / sum;
#pragma unroll
      for (int t = 0; t < 16; ++t) wSm[tid][t] = s[t] * inv;
    }
    __syncthreads();

    {  // chunk[c][d] = sum_t w[c,t] * feats[c*16+t][d]
      int d = tid;
#pragma unroll
      for (int c = 0; c < 2; ++c) {
        float a = 0.f;
#pragma unroll
        for (int t = 0; t < 16; ++t) {
          float f = (float)fH[c * 16 + t][d] + (float)fL[c * 16 + t][d];
          a = fmaf(wSm[c][t], f, a);
        }
        chunkS[c][d] = a;
      }
    }
    __syncthreads();

    {  // proj via MFMA, B double-buffered
      f32x4 acc3 = (f32x4){0.f, 0.f, 0.f, 0.f};
      bf16x8 p_bh[2], p_bl[2];
      {
        const size_t row = (size_t)jout * 256 + 8 * quad;
        p_bh[0] = *(const bf16x8*)(projTH + row);
        p_bl[0] = *(const bf16x8*)(projTL + row);
      }
#pragma unroll
      for (int s = 0; s < 8; ++s) {
        const int cb = s & 1, nb = cb ^ 1;
        if (s < 7) {
          const size_t row = (size_t)jout * 256 + 32 * (s + 1) + 8 * quad;
          p_bh[nb] = *(const bf16x8*)(projTH + row);
          p_bl[nb] = *(const bf16x8*)(projTL + row);
        }
        bf16x8 ah = (bf16x8)(__bf16)0.f, al = (bf16x8)(__bf16)0.f;
        if (l15 < 2) {
          const float* cs = &chunkS[l15][32 * s + 8 * quad];
          float4 u0 = *(const float4*)cs, u1 = *(const float4*)(cs + 4);
          float vals[8] = {u0.x, u0.y, u0.z, u0.w, u1.x, u1.y, u1.z, u1.w};
#pragma unroll
          for (int j = 0; j < 8; ++j) {
            __bf16 h = (__bf16)vals[j];
            ah[j] = h;
            al[j] = (__bf16)(vals[j] - (float)h);
          }
        }
        acc3 = __builtin_amdgcn_mfma_f32_16x16x32_bf16(ah, p_bh[cb], acc3, 0, 0, 0);
        acc3 = __builtin_amdgcn_mfma_f32_16x16x32_bf16(al, p_bh[cb], acc3, 0, 0, 0);
        acc3 = __builtin_amdgcn_mfma_f32_16x16x32_bf16(ah, p_bl[cb], acc3, 0, 0, 0);
      }
      if (jout < 60 && quad == 0) {
#pragma unroll
        for (int r = 0; r < 2; ++r) {
          float a = acc3[r] + pbias;
          params_out[((size_t)tk * 2 + r) * 60 + jout] = 1.f / (1.f + __expf(-a));
        }
      }
    }
    // no barrier needed before loop-around: xtile untouched since pre-GEMM1-
    // epilogue barrier; top-of-loop writes are ordered by the chunkS barrier.
  }
}

// ============ K2: 2-layer ansatz, one statevector per wave ============
__global__ __launch_bounds__(256) void k2_ansatz(const float* __restrict__ params,
                                                 float2* __restrict__ evolved) {
  const int gid = blockIdx.x * 256 + threadIdx.x;
  const int gw = gid >> 6, lane = gid & 63;
  const float4* p4 = (const float4*)(params + (size_t)gw * NCP);
  float p[60];
#pragma unroll
  for (int i = 0; i < 15; ++i) {
    float4 v = p4[i];
    p[4 * i + 0] = v.x; p[4 * i + 1] = v.y; p[4 * i + 2] = v.z; p[4 * i + 3] = v.w;
  }
  float re = (lane == 0) ? 1.f : 0.f, im = 0.f;
  ansatz_layer(re, im, lane, p);
  ansatz_layer(re, im, lane, p + 30);
  evolved[gid] = make_float2(re, im);
}

// ============ K3: LCU mix + qff ansatz + expvals + head (512 thr) ============
__global__ __launch_bounds__(512) void k3_head(
    const float2* __restrict__ evolved, const float* __restrict__ mix_re,
    const float* __restrict__ mix_im, const float* __restrict__ qff,
    const float* __restrict__ out_w, const float* __restrict__ out_b,
    const float* __restrict__ ln_g, const float* __restrict__ ln_b,
    const float* __restrict__ cls_w1, const float* __restrict__ cls_b1,
    const float* __restrict__ cls_w2, const float* __restrict__ cls_b2,
    float* __restrict__ outp) {
  const int b = blockIdx.x, tid = threadIdx.x, wv = tid >> 6, lane = tid & 63;
  __shared__ float mreS[8][64], mimS[8][64];
  __shared__ float qfeatS[18];
  __shared__ float outS[DD];
  __shared__ float redS[8];
  __shared__ float clsR[2][DD];

  // mix: wave wv handles 16 chunks
  float are = 0.f, aim = 0.f;
#pragma unroll 4
  for (int t = wv * 16; t < wv * 16 + 16; ++t) {
    float2 e = evolved[((size_t)b * NCH + t) * QDIM + lane];
    float cr = mix_re[t], ci = mix_im[t];
    are = fmaf(cr, e.x, are); are = fmaf(-ci, e.y, are);
    aim = fmaf(cr, e.y, aim); aim = fmaf(ci, e.x, aim);
  }
  mreS[wv][lane] = are; mimS[wv][lane] = aim;
  __syncthreads();

  if (wv == 0) {
    float r0 = mix_re[lane], i0 = mix_im[lane];
    float r1 = mix_re[lane + 64], i1 = mix_im[lane + 64];
    float sp = sqrtf(r0 * r0 + i0 * i0) + sqrtf(r1 * r1 + i1 * i1);
    float S = wave_sum(sp) + 1e-8f;
    float re = 0.f, im = 0.f;
#pragma unroll
    for (int w = 0; w < 8; ++w) { re += mreS[w][lane]; im += mimS[w][lane]; }
    float invS = 1.f / S;
    re *= invS; im *= invS;
    float n2 = wave_sum(re * re + im * im);
    float scl = 1.f / (sqrtf(n2) + 1e-9f);
    re *= scl; im *= scl;
    float qp[30];
#pragma unroll
    for (int i = 0; i < 30; ++i) qp[i] = qff[i];
    ansatz_layer(re, im, lane, qp);
#pragma unroll
    for (int q = 0; q < 6; ++q) {
      int m = 1 << (5 - q);
      float pre = __shfl_xor(re, m, 64), pim = __shfl_xor(im, m, 64);
      float vx = re * pre + im * pim;
      float vy = (lane & m) ? (im * pre - re * pim) : (re * pim - im * pre);
      float vz = (lane & m) ? -(re * re + im * im) : (re * re + im * im);
      vx = wave_sum(vx); vy = wave_sum(vy); vz = wave_sum(vz);
      if (lane == 0) { qfeatS[q] = vx; qfeatS[6 + q] = vy; qfeatS[12 + q] = vz; }
    }
  }
  __syncthreads();

  // out = qfeat @ out_w + out_b, then LayerNorm (tid<256 active)
  float o = 0.f, dv = 0.f;
  if (tid < 256) {
    o = out_b[tid];
#pragma unroll
    for (int k = 0; k < 18; ++k) o = fmaf(qfeatS[k], out_w[k * DD + tid], o);
    float s1 = wave_sum(o);
    if (lane == 0) redS[wv] = s1;
  }
  __syncthreads();
  float mu = (redS[0] + redS[1] + redS[2] + redS[3]) * (1.f / 256.f);
  if (tid < 256) {
    dv = o - mu;
    float s2 = wave_sum(dv * dv);
    if (lane == 0) redS[wv] = s2;
  }
  __syncthreads();
  float var = (redS[0] + redS[1] + redS[2] + redS[3]) * (1.f / 256.f);
  if (tid < 256) {
    outS[tid] = dv / sqrtf(var + 1e-5f) * ln_g[tid] + ln_b[tid];
  }
  __syncthreads();

  // classifier: 512 threads = 256 outputs x 2 d-halves
  {
    const int dd = tid & 255, hh = tid >> 8;
    float r = (hh == 0) ? cls_b1[dd] : 0.f;
#pragma unroll 8
    for (int d = hh * 128; d < hh * 128 + 128; ++d)
      r = fmaf(outS[d], cls_w1[(size_t)d * DD + dd], r);
    clsR[hh][dd] = r;
  }
  __syncthreads();
  if (tid < 256) {
    float r = fmaxf(clsR[0][tid] + clsR[1][tid], 0.f);
    float p0 = wave_sum(r * cls_w2[tid * 2 + 0]);
    float p1 = wave_sum(r * cls_w2[tid * 2 + 1]);
    if (lane == 0) { mreS[0][wv] = p0; mreS[1][wv] = p1; }
  }
  __syncthreads();
  if (tid == 0) {
    outp[b * 2 + 0] = (mreS[0][0] + mreS[0][1]) + (mreS[0][2] + mreS[0][3]) + cls_b2[0];
    outp[b * 2 + 1] = (mreS[1][0] + mreS[1][1]) + (mreS[1][2] + mreS[1][3]) + cls_b2[1];
  }
}

extern "C" void kernel_launch(void* const* d_in, const int* in_sizes, int n_in,
                              void* d_out, int out_size, void* d_ws, size_t ws_size,
                              hipStream_t stream) {
  const float* x      = (const float*)d_in[0];
  const float* emb_w  = (const float*)d_in[1];
  const float* emb_b  = (const float*)d_in[2];
  const float* att_w1 = (const float*)d_in[3];
  const float* att_b1 = (const float*)d_in[4];
  const float* att_w2 = (const float*)d_in[5];
  // d_in[6] att_b2: unused (softmax shift-invariant)
  const float* proj_w = (const float*)d_in[7];
  const float* proj_b = (const float*)d_in[8];
  const float* mix_re = (const float*)d_in[9];
  const float* mix_im = (const float*)d_in[10];
  const float* qff    = (const float*)d_in[11];
  const float* out_w  = (const float*)d_in[12];
  const float* out_b  = (const float*)d_in[13];
  const float* ln_g   = (const float*)d_in[14];
  const float* ln_b   = (const float*)d_in[15];
  const float* cls_w1 = (const float*)d_in[16];
  const float* cls_b1 = (const float*)d_in[17];
  const float* cls_w2 = (const float*)d_in[18];
  const float* cls_b2 = (const float*)d_in[19];

  char* ws = (char*)d_ws;
  float*  params  = (float*)ws;                      // 16384*60*4 = 3,932,160
  float2* evolved = (float2*)(ws + 3932160);         // 16384*64*8 = 8,388,608
  size_t off = 3932160 + 8388608;
  __bf16* embH   = (__bf16*)(ws + off); off += 32768;
  __bf16* embL   = (__bf16*)(ws + off); off += 32768;
  __bf16* attH   = (__bf16*)(ws + off); off += 65536;
  __bf16* attL   = (__bf16*)(ws + off); off += 65536;
  __bf16* projTH = (__bf16*)(ws + off); off += 32768;
  __bf16* projTL = (__bf16*)(ws + off); off += 32768;

  k0_prep<<<256, 256, 0, stream>>>(emb_w, att_w1, proj_w,
                                   embH, embL, attH, attL, projTH, projTL);
  k1_feats_attn_proj<<<GRID1, 256, 0, stream>>>(
      x, emb_b, att_b1, att_w2, proj_b,
      embH, embL, attH, attL, projTH, projTL, params);
  k2_ansatz<<<BB * NCH * QDIM / 256, 256, 0, stream>>>(params, evolved);
  k3_head<<<BB, 512, 0, stream>>>(evolved, mix_re, mix_im, qff, out_w, out_b,
                                  ln_g, ln_b, cls_w1, cls_b1, cls_w2, cls_b2,
                                  (float*)d_out);
}

// Round 5
// 391.466 us; speedup vs baseline: 1.2647x; 1.2647x over previous
//
#include <hip/hip_runtime.h>
#include <math.h>

#define NQ    6
#define QDIM  64
#define BB    128
#define CC    64
#define TT    2048
#define DD    256
#define NCH   128
#define CHLEN 16
#define HH    128
#define NCP   60

typedef __bf16 bf16x8 __attribute__((ext_vector_type(8)));
typedef float  f32x4  __attribute__((ext_vector_type(4)));

__device__ __forceinline__ float fast_tanh(float x) {
  float e = __expf(2.f * x);
  return 1.f - 2.f / (e + 1.f);
}

__device__ __forceinline__ float wave_sum(float v) {
#pragma unroll
  for (int off = 32; off >= 1; off >>= 1) v += __shfl_xor(v, off, 64);
  return v;
}

// ---- quantum gates: one statevector per wave, (re,im) per lane ----
__device__ __forceinline__ void g_rx(float& re, float& im, int lane, int m, float half) {
  float c = __cosf(half), s = __sinf(half);
  float pre = __shfl_xor(re, m, 64);
  float pim = __shfl_xor(im, m, 64);
  float nre = c * re + s * pim;
  float nim = c * im - s * pre;
  re = nre; im = nim;
}
__device__ __forceinline__ void g_ry(float& re, float& im, int lane, int m, float half) {
  float c = __cosf(half), s = __sinf(half);
  float pre = __shfl_xor(re, m, 64);
  float pim = __shfl_xor(im, m, 64);
  float sg = (lane & m) ? s : -s;
  re = c * re + sg * pre;
  im = c * im + sg * pim;
}
__device__ __forceinline__ void g_rz(float& re, float& im, int lane, int m, float half) {
  float c = __cosf(half), s = __sinf(half);
  float sg = (lane & m) ? s : -s;
  float nre = c * re - sg * im;
  float nim = c * im + sg * re;
  re = nre; im = nim;
}
__device__ __forceinline__ void g_crx(float& re, float& im, int lane, int mc, int mt, float half) {
  float c = __cosf(half), s = __sinf(half);
  float pre = __shfl_xor(re, mt, 64);
  float pim = __shfl_xor(im, mt, 64);
  if (lane & mc) {
    float nre = c * re + s * pim;
    float nim = c * im - s * pre;
    re = nre; im = nim;
  }
}
__device__ __forceinline__ void ansatz_layer(float& re, float& im, int lane,
                                             const float* p) {
#pragma unroll
  for (int q = 0; q < 6; ++q) {
    int m = 1 << (5 - q);
    g_rx(re, im, lane, m, 0.5f * p[3 * q + 0]);
    g_ry(re, im, lane, m, 0.5f * p[3 * q + 1]);
    g_rz(re, im, lane, m, 0.5f * p[3 * q + 2]);
  }
#pragma unroll
  for (int q = 0; q < 6; ++q)
    g_crx(re, im, lane, 1 << (5 - q), 1 << (5 - ((q + 1) % 6)), 0.5f * p[18 + q]);
#pragma unroll
  for (int q = 5; q >= 0; --q)
    g_crx(re, im, lane, 1 << (5 - q), 1 << (5 - ((q + 5) % 6)), 0.5f * p[24 + (5 - q)]);
}

// ============ K0: one-time weight prep: split-bf16 + transpose ============
__global__ __launch_bounds__(256) void k0_prep(
    const float* __restrict__ emb_w, const float* __restrict__ att_w1,
    const float* __restrict__ proj_w,
    __bf16* __restrict__ embH, __bf16* __restrict__ embL,
    __bf16* __restrict__ attH, __bf16* __restrict__ attL,
    __bf16* __restrict__ projTH, __bf16* __restrict__ projTL) {
  int idx = blockIdx.x * 256 + threadIdx.x;
  if (idx < 16384) {                       // emb: 256d x 64k
    int d = idx >> 6, k = idx & 63;
    float v = emb_w[k * 256 + d];
    __bf16 h = (__bf16)v;
    embH[idx] = h; embL[idx] = (__bf16)(v - (float)h);
  } else if (idx < 49152) {                // att: 128j x 256d
    int i = idx - 16384;
    int j = i >> 8, d = i & 255;
    float v = att_w1[d * 128 + j];
    __bf16 h = (__bf16)v;
    attH[i] = h; attL[i] = (__bf16)(v - (float)h);
  } else {                                 // projT: 64n x 256d (rows>=60 zero)
    int i = idx - 49152;
    int n = i >> 8, d = i & 255;
    float v = (n < 60) ? proj_w[d * 60 + n] : 0.f;
    __bf16 h = (__bf16)v;
    projTH[i] = h; projTL[i] = (__bf16)(v - (float)h);
  }
}

// ============ K1: per-(b,chunk-pair) fused embed+attn+softmax+agg+proj ============
// Split-bf16 3-product MFMA. m89 layouts: A[m=lane&15][k=quad*8+j],
// B[n=lane&15][k=quad*8+j], C: n=lane&15, m=quad*4+reg.
// GEMM1 A comes straight from global x (lane l15 <-> contiguous t); no xtile.
// LDS ~37 KB -> 4 blocks/CU; launch_bounds(256,4) caps VGPR at 128.
__global__ __launch_bounds__(256, 4) void k1_feats_attn_proj(
    const float* __restrict__ x, const float* __restrict__ emb_b,
    const float* __restrict__ att_b1, const float* __restrict__ att_w2,
    const float* __restrict__ proj_b,
    const __bf16* __restrict__ embH, const __bf16* __restrict__ embL,
    const __bf16* __restrict__ attH, const __bf16* __restrict__ attL,
    const __bf16* __restrict__ projTH, const __bf16* __restrict__ projTL,
    float* __restrict__ params_out) {
  const int blk = blockIdx.x;            // 8192 = 128 b x 64 chunk-pairs
  const int b = blk >> 6, cp = blk & 63;
  const int tid = threadIdx.x, wv = tid >> 6, lane = tid & 63;
  const int l15 = lane & 15, quad = lane >> 4;

  __shared__ __bf16 fH[32][264];         // feats hi, word-stride 132
  __shared__ __bf16 fL[32][264];
  __shared__ float  scoreP[4][32];
  __shared__ float  wSm[2][16];
  __shared__ float  chunkS[2][256];

  // ---- GEMM1: feats[32][256] = x^T @ emb_w; A direct from global ----
  {
    // load raw A: a_raw[mt][s][j] = x[b][32s+8q+j][cp*32 + mt*16 + l15]
    const float* xb = x + (size_t)b * 64 * 2048 + cp * 32 + l15;
    float a_raw[2][2][8];
#pragma unroll
    for (int mt = 0; mt < 2; ++mt)
#pragma unroll
      for (int s = 0; s < 2; ++s)
#pragma unroll
        for (int j = 0; j < 8; ++j)
          a_raw[mt][s][j] = xb[(size_t)(32 * s + 8 * quad + j) * 2048 + mt * 16];
    float biasv[4];
#pragma unroll
    for (int nt = 0; nt < 4; ++nt) biasv[nt] = emb_b[wv * 64 + nt * 16 + l15];
    bf16x8 ah[2][2], al[2][2];
#pragma unroll
    for (int mt = 0; mt < 2; ++mt)
#pragma unroll
      for (int s = 0; s < 2; ++s)
#pragma unroll
        for (int j = 0; j < 8; ++j) {
          float v = a_raw[mt][s][j];
          __bf16 h = (__bf16)v;
          ah[mt][s][j] = h;
          al[mt][s][j] = (__bf16)(v - (float)h);
        }

    f32x4 acc[4][2];                     // [nt][mt]
#pragma unroll
    for (int nt = 0; nt < 4; ++nt)
#pragma unroll
      for (int mt = 0; mt < 2; ++mt) acc[nt][mt] = (f32x4){0.f, 0.f, 0.f, 0.f};

    bf16x8 ebh[2][2], ebl[2][2];         // [buf][s]
    {
      const size_t row = (size_t)(wv * 64 + l15) * 64 + 8 * quad;
#pragma unroll
      for (int s = 0; s < 2; ++s) {
        ebh[0][s] = *(const bf16x8*)(embH + row + 32 * s);
        ebl[0][s] = *(const bf16x8*)(embL + row + 32 * s);
      }
    }
#pragma unroll
    for (int nt = 0; nt < 4; ++nt) {
      const int cb = nt & 1, nb = cb ^ 1;
      if (nt < 3) {
        const size_t row = (size_t)(wv * 64 + (nt + 1) * 16 + l15) * 64 + 8 * quad;
#pragma unroll
        for (int s = 0; s < 2; ++s) {
          ebh[nb][s] = *(const bf16x8*)(embH + row + 32 * s);
          ebl[nb][s] = *(const bf16x8*)(embL + row + 32 * s);
        }
      }
#pragma unroll
      for (int mt = 0; mt < 2; ++mt) {
        acc[nt][mt] = __builtin_amdgcn_mfma_f32_16x16x32_bf16(ah[mt][0], ebh[cb][0], acc[nt][mt], 0, 0, 0);
        acc[nt][mt] = __builtin_amdgcn_mfma_f32_16x16x32_bf16(al[mt][0], ebh[cb][0], acc[nt][mt], 0, 0, 0);
        acc[nt][mt] = __builtin_amdgcn_mfma_f32_16x16x32_bf16(ah[mt][0], ebl[cb][0], acc[nt][mt], 0, 0, 0);
        acc[nt][mt] = __builtin_amdgcn_mfma_f32_16x16x32_bf16(ah[mt][1], ebh[cb][1], acc[nt][mt], 0, 0, 0);
        acc[nt][mt] = __builtin_amdgcn_mfma_f32_16x16x32_bf16(al[mt][1], ebh[cb][1], acc[nt][mt], 0, 0, 0);
        acc[nt][mt] = __builtin_amdgcn_mfma_f32_16x16x32_bf16(ah[mt][1], ebl[cb][1], acc[nt][mt], 0, 0, 0);
      }
    }
    // epilogue: +bias, split hi/lo into LDS
#pragma unroll
    for (int nt = 0; nt < 4; ++nt) {
      int d = wv * 64 + nt * 16 + l15;
#pragma unroll
      for (int mt = 0; mt < 2; ++mt)
#pragma unroll
        for (int r = 0; r < 4; ++r) {
          int trow = mt * 16 + quad * 4 + r;
          float v = acc[nt][mt][r] + biasv[nt];
          __bf16 h = (__bf16)v;
          fH[trow][d] = h;
          fL[trow][d] = (__bf16)(v - (float)h);
        }
    }
  }
  __syncthreads();

  // ---- GEMM2: h = tanh(feats @ att_w1 + b1), fused scores; B double-buffered ----
  {
    float w2v[2], b1v[2];
#pragma unroll
    for (int jt = 0; jt < 2; ++jt) {
      int j = wv * 32 + jt * 16 + l15;
      w2v[jt] = att_w2[j];
      b1v[jt] = att_b1[j];
    }
    f32x4 acc2[2][2];
#pragma unroll
    for (int mt = 0; mt < 2; ++mt)
#pragma unroll
      for (int jt = 0; jt < 2; ++jt) acc2[mt][jt] = (f32x4){0.f, 0.f, 0.f, 0.f};
    bf16x8 g_bh[2][2], g_bl[2][2];  // [buf][jt]
#pragma unroll
    for (int jt = 0; jt < 2; ++jt) {
      const size_t row = (size_t)(wv * 32 + jt * 16 + l15) * 256 + 8 * quad;
      g_bh[0][jt] = *(const bf16x8*)(attH + row);
      g_bl[0][jt] = *(const bf16x8*)(attL + row);
    }
#pragma unroll
    for (int s = 0; s < 8; ++s) {
      const int cb = s & 1, nb = cb ^ 1;
      if (s < 7) {
#pragma unroll
        for (int jt = 0; jt < 2; ++jt) {
          const size_t row = (size_t)(wv * 32 + jt * 16 + l15) * 256 + 32 * (s + 1) + 8 * quad;
          g_bh[nb][jt] = *(const bf16x8*)(attH + row);
          g_bl[nb][jt] = *(const bf16x8*)(attL + row);
        }
      }
      bf16x8 fa[2], fb[2];
#pragma unroll
      for (int mt = 0; mt < 2; ++mt) {
        fa[mt] = *(const bf16x8*)&fH[mt * 16 + l15][32 * s + 8 * quad];
        fb[mt] = *(const bf16x8*)&fL[mt * 16 + l15][32 * s + 8 * quad];
      }
#pragma unroll
      for (int jt = 0; jt < 2; ++jt)
#pragma unroll
        for (int mt = 0; mt < 2; ++mt) {
          acc2[mt][jt] = __builtin_amdgcn_mfma_f32_16x16x32_bf16(fa[mt], g_bh[cb][jt], acc2[mt][jt], 0, 0, 0);
          acc2[mt][jt] = __builtin_amdgcn_mfma_f32_16x16x32_bf16(fb[mt], g_bh[cb][jt], acc2[mt][jt], 0, 0, 0);
          acc2[mt][jt] = __builtin_amdgcn_mfma_f32_16x16x32_bf16(fa[mt], g_bl[cb][jt], acc2[mt][jt], 0, 0, 0);
        }
    }
#pragma unroll
    for (int mt = 0; mt < 2; ++mt)
#pragma unroll
      for (int r = 0; r < 4; ++r) {
        float sc = fast_tanh(acc2[mt][0][r] + b1v[0]) * w2v[0] +
                   fast_tanh(acc2[mt][1][r] + b1v[1]) * w2v[1];
        sc += __shfl_xor(sc, 1, 64);
        sc += __shfl_xor(sc, 2, 64);
        sc += __shfl_xor(sc, 4, 64);
        sc += __shfl_xor(sc, 8, 64);
        if (l15 == 0) scoreP[wv][mt * 16 + quad * 4 + r] = sc;
      }
  }
  __syncthreads();

  if (tid < 2) {  // softmax over 16 per chunk (att_b2 dropped: shift-invariant)
    float s[16], mx = -1e30f;
#pragma unroll
    for (int t = 0; t < 16; ++t) {
      int tt = tid * 16 + t;
      s[t] = (scoreP[0][tt] + scoreP[1][tt]) + (scoreP[2][tt] + scoreP[3][tt]);
      mx = fmaxf(mx, s[t]);
    }
    float sum = 0.f;
#pragma unroll
    for (int t = 0; t < 16; ++t) { s[t] = __expf(s[t] - mx); sum += s[t]; }
    float inv = 1.f / sum;
#pragma unroll
    for (int t = 0; t < 16; ++t) wSm[tid][t] = s[t] * inv;
  }
  __syncthreads();

  {  // chunk[c][d] = sum_t w[c,t] * feats[c*16+t][d]
    int d = tid;
#pragma unroll
    for (int c = 0; c < 2; ++c) {
      float a = 0.f;
#pragma unroll
      for (int t = 0; t < 16; ++t) {
        float f = (float)fH[c * 16 + t][d] + (float)fL[c * 16 + t][d];
        a = fmaf(wSm[c][t], f, a);
      }
      chunkS[c][d] = a;
    }
  }
  __syncthreads();

  {  // proj via MFMA, B double-buffered
    const int jout = wv * 16 + l15;
    f32x4 acc3 = (f32x4){0.f, 0.f, 0.f, 0.f};
    bf16x8 p_bh[2], p_bl[2];
    {
      const size_t row = (size_t)jout * 256 + 8 * quad;
      p_bh[0] = *(const bf16x8*)(projTH + row);
      p_bl[0] = *(const bf16x8*)(projTL + row);
    }
#pragma unroll
    for (int s = 0; s < 8; ++s) {
      const int cb = s & 1, nb = cb ^ 1;
      if (s < 7) {
        const size_t row = (size_t)jout * 256 + 32 * (s + 1) + 8 * quad;
        p_bh[nb] = *(const bf16x8*)(projTH + row);
        p_bl[nb] = *(const bf16x8*)(projTL + row);
      }
      bf16x8 ah = (bf16x8)(__bf16)0.f, al = (bf16x8)(__bf16)0.f;
      if (l15 < 2) {
        const float* cs = &chunkS[l15][32 * s + 8 * quad];
        float4 u0 = *(const float4*)cs, u1 = *(const float4*)(cs + 4);
        float vals[8] = {u0.x, u0.y, u0.z, u0.w, u1.x, u1.y, u1.z, u1.w};
#pragma unroll
        for (int j = 0; j < 8; ++j) {
          __bf16 h = (__bf16)vals[j];
          ah[j] = h;
          al[j] = (__bf16)(vals[j] - (float)h);
        }
      }
      acc3 = __builtin_amdgcn_mfma_f32_16x16x32_bf16(ah, p_bh[cb], acc3, 0, 0, 0);
      acc3 = __builtin_amdgcn_mfma_f32_16x16x32_bf16(al, p_bh[cb], acc3, 0, 0, 0);
      acc3 = __builtin_amdgcn_mfma_f32_16x16x32_bf16(ah, p_bl[cb], acc3, 0, 0, 0);
    }
    if (jout < 60 && quad == 0) {
      float pbias = proj_b[jout];
#pragma unroll
      for (int r = 0; r < 2; ++r) {
        float a = acc3[r] + pbias;
        params_out[((size_t)blk * 2 + r) * 60 + jout] = 1.f / (1.f + __expf(-a));
      }
    }
  }
}

// ============ K2: 2-layer ansatz, one statevector per wave ============
__global__ __launch_bounds__(256) void k2_ansatz(const float* __restrict__ params,
                                                 float2* __restrict__ evolved) {
  const int gid = blockIdx.x * 256 + threadIdx.x;
  const int gw = gid >> 6, lane = gid & 63;
  const float4* p4 = (const float4*)(params + (size_t)gw * NCP);
  float p[60];
#pragma unroll
  for (int i = 0; i < 15; ++i) {
    float4 v = p4[i];
    p[4 * i + 0] = v.x; p[4 * i + 1] = v.y; p[4 * i + 2] = v.z; p[4 * i + 3] = v.w;
  }
  float re = (lane == 0) ? 1.f : 0.f, im = 0.f;
  ansatz_layer(re, im, lane, p);
  ansatz_layer(re, im, lane, p + 30);
  evolved[gid] = make_float2(re, im);
}

// ============ K3: LCU mix + qff ansatz + expvals + head (512 thr) ============
__global__ __launch_bounds__(512) void k3_head(
    const float2* __restrict__ evolved, const float* __restrict__ mix_re,
    const float* __restrict__ mix_im, const float* __restrict__ qff,
    const float* __restrict__ out_w, const float* __restrict__ out_b,
    const float* __restrict__ ln_g, const float* __restrict__ ln_b,
    const float* __restrict__ cls_w1, const float* __restrict__ cls_b1,
    const float* __restrict__ cls_w2, const float* __restrict__ cls_b2,
    float* __restrict__ outp) {
  const int b = blockIdx.x, tid = threadIdx.x, wv = tid >> 6, lane = tid & 63;
  __shared__ float mreS[8][64], mimS[8][64];
  __shared__ float qfeatS[18];
  __shared__ float outS[DD];
  __shared__ float redS[8];
  __shared__ float clsR[2][DD];

  float are = 0.f, aim = 0.f;
#pragma unroll 4
  for (int t = wv * 16; t < wv * 16 + 16; ++t) {
    float2 e = evolved[((size_t)b * NCH + t) * QDIM + lane];
    float cr = mix_re[t], ci = mix_im[t];
    are = fmaf(cr, e.x, are); are = fmaf(-ci, e.y, are);
    aim = fmaf(cr, e.y, aim); aim = fmaf(ci, e.x, aim);
  }
  mreS[wv][lane] = are; mimS[wv][lane] = aim;
  __syncthreads();

  if (wv == 0) {
    float r0 = mix_re[lane], i0 = mix_im[lane];
    float r1 = mix_re[lane + 64], i1 = mix_im[lane + 64];
    float sp = sqrtf(r0 * r0 + i0 * i0) + sqrtf(r1 * r1 + i1 * i1);
    float S = wave_sum(sp) + 1e-8f;
    float re = 0.f, im = 0.f;
#pragma unroll
    for (int w = 0; w < 8; ++w) { re += mreS[w][lane]; im += mimS[w][lane]; }
    float invS = 1.f / S;
    re *= invS; im *= invS;
    float n2 = wave_sum(re * re + im * im);
    float scl = 1.f / (sqrtf(n2) + 1e-9f);
    re *= scl; im *= scl;
    float qp[30];
#pragma unroll
    for (int i = 0; i < 30; ++i) qp[i] = qff[i];
    ansatz_layer(re, im, lane, qp);
#pragma unroll
    for (int q = 0; q < 6; ++q) {
      int m = 1 << (5 - q);
      float pre = __shfl_xor(re, m, 64), pim = __shfl_xor(im, m, 64);
      float vx = re * pre + im * pim;
      float vy = (lane & m) ? (im * pre - re * pim) : (re * pim - im * pre);
      float vz = (lane & m) ? -(re * re + im * im) : (re * re + im * im);
      vx = wave_sum(vx); vy = wave_sum(vy); vz = wave_sum(vz);
      if (lane == 0) { qfeatS[q] = vx; qfeatS[6 + q] = vy; qfeatS[12 + q] = vz; }
    }
  }
  __syncthreads();

  float o = 0.f, dv = 0.f;
  if (tid < 256) {
    o = out_b[tid];
#pragma unroll
    for (int k = 0; k < 18; ++k) o = fmaf(qfeatS[k], out_w[k * DD + tid], o);
    float s1 = wave_sum(o);
    if (lane == 0) redS[wv] = s1;
  }
  __syncthreads();
  float mu = (redS[0] + redS[1] + redS[2] + redS[3]) * (1.f / 256.f);
  if (tid < 256) {
    dv = o - mu;
    float s2 = wave_sum(dv * dv);
    if (lane == 0) redS[wv] = s2;
  }
  __syncthreads();
  float var = (redS[0] + redS[1] + redS[2] + redS[3]) * (1.f / 256.f);
  if (tid < 256) {
    outS[tid] = dv / sqrtf(var + 1e-5f) * ln_g[tid] + ln_b[tid];
  }
  __syncthreads();

  {
    const int dd = tid & 255, hh = tid >> 8;
    float r = (hh == 0) ? cls_b1[dd] : 0.f;
#pragma unroll 8
    for (int d = hh * 128; d < hh * 128 + 128; ++d)
      r = fmaf(outS[d], cls_w1[(size_t)d * DD + dd], r);
    clsR[hh][dd] = r;
  }
  __syncthreads();
  if (tid < 256) {
    float r = fmaxf(clsR[0][tid] + clsR[1][tid], 0.f);
    float p0 = wave_sum(r * cls_w2[tid * 2 + 0]);
    float p1 = wave_sum(r * cls_w2[tid * 2 + 1]);
    if (lane == 0) { mreS[0][wv] = p0; mreS[1][wv] = p1; }
  }
  __syncthreads();
  if (tid == 0) {
    outp[b * 2 + 0] = (mreS[0][0] + mreS[0][1]) + (mreS[0][2] + mreS[0][3]) + cls_b2[0];
    outp[b * 2 + 1] = (mreS[1][0] + mreS[1][1]) + (mreS[1][2] + mreS[1][3]) + cls_b2[1];
  }
}

extern "C" void kernel_launch(void* const* d_in, const int* in_sizes, int n_in,
                              void* d_out, int out_size, void* d_ws, size_t ws_size,
                              hipStream_t stream) {
  const float* x      = (const float*)d_in[0];
  const float* emb_w  = (const float*)d_in[1];
  const float* emb_b  = (const float*)d_in[2];
  const float* att_w1 = (const float*)d_in[3];
  const float* att_b1 = (const float*)d_in[4];
  const float* att_w2 = (const float*)d_in[5];
  // d_in[6] att_b2: unused (softmax shift-invariant)
  const float* proj_w = (const float*)d_in[7];
  const float* proj_b = (const float*)d_in[8];
  const float* mix_re = (const float*)d_in[9];
  const float* mix_im = (const float*)d_in[10];
  const float* qff    = (const float*)d_in[11];
  const float* out_w  = (const float*)d_in[12];
  const float* out_b  = (const float*)d_in[13];
  const float* ln_g   = (const float*)d_in[14];
  const float* ln_b   = (const float*)d_in[15];
  const float* cls_w1 = (const float*)d_in[16];
  const float* cls_b1 = (const float*)d_in[17];
  const float* cls_w2 = (const float*)d_in[18];
  const float* cls_b2 = (const float*)d_in[19];

  char* ws = (char*)d_ws;
  float*  params  = (float*)ws;                      // 16384*60*4 = 3,932,160
  float2* evolved = (float2*)(ws + 3932160);         // 16384*64*8 = 8,388,608
  size_t off = 3932160 + 8388608;
  __bf16* embH   = (__bf16*)(ws + off); off += 32768;
  __bf16* embL   = (__bf16*)(ws + off); off += 32768;
  __bf16* attH   = (__bf16*)(ws + off); off += 65536;
  __bf16* attL   = (__bf16*)(ws + off); off += 65536;
  __bf16* projTH = (__bf16*)(ws + off); off += 32768;
  __bf16* projTL = (__bf16*)(ws + off); off += 32768;

  k0_prep<<<256, 256, 0, stream>>>(emb_w, att_w1, proj_w,
                                   embH, embL, attH, attL, projTH, projTL);
  k1_feats_attn_proj<<<BB * 64, 256, 0, stream>>>(
      x, emb_b, att_b1, att_w2, proj_b,
      embH, embL, attH, attL, projTH, projTL, params);
  k2_ansatz<<<BB * NCH * QDIM / 256, 256, 0, stream>>>(params, evolved);
  k3_head<<<BB, 512, 0, stream>>>(evolved, mix_re, mix_im, qff, out_w, out_b,
                                  ln_g, ln_b, cls_w1, cls_b1, cls_w2, cls_b2,
                                  (float*)d_out);
}